// Round 3
// baseline (499.610 us; speedup 1.0000x reference)
//
#include <hip/hip_runtime.h>
#include <math.h>

// Problem constants (from reference)
#define BATCH 64
#define TDIM 512
#define FEAT 2048
#define HID 1024
#define KDIM 512
#define MROWS (BATCH * TDIM)  // 32768 flat feats rows
#define TCH 16                // k4 time-chunks
#define TCLEN (TDIM / TCH)    // 32 t per chunk

#define NSTEP (FEAT / 64)     // 32 K-steps in the GEMM
#define BSLOT (KDIM * 8)      // 4096 16B-slots per packed B tile
#define BTILE (BSLOT * 8)     // 32768 bf16 elements per packed B tile

typedef __attribute__((ext_vector_type(8))) short short8;
typedef __attribute__((ext_vector_type(4))) float floatx4;

// global -> LDS direct DMA, 16B per lane; LDS dest is wave-uniform base,
// lane i lands at base + i*16 (per-lane LDS address is NOT honored).
#define GLL16(g, l)                                                     \
    __builtin_amdgcn_global_load_lds(                                   \
        (const __attribute__((address_space(1))) void*)(g),             \
        (__attribute__((address_space(3))) void*)(l), 16, 0, 0)

// ---------------------------------------------------------------------------
// f32 -> bf16 (round-to-nearest-even)
// ---------------------------------------------------------------------------
__device__ __forceinline__ unsigned short f2bf(float x) {
    unsigned int u = __float_as_uint(x);
    u += 0x7FFFu + ((u >> 16) & 1u);
    return (unsigned short)(u >> 16);
}

// ---------------------------------------------------------------------------
// k0n: blocks [0,256): PACK U f32 -> bf16 in K-step-tile-major, pre-swizzled
//      order: slot s = t*4096 + r*8 + ((c)^(r&7)) holds U[r][t*64+c*8..+8].
//      Each 64 KB tile is then a contiguous sequential GLL16 source in k2n.
//      blocks [256,8448): Whb[b,k] = hidden[b]·W[k] + bias[k]
// ---------------------------------------------------------------------------
__global__ __launch_bounds__(256) void k0n(const float* __restrict__ U,
                                           const float* __restrict__ hidden,
                                           const float* __restrict__ W,
                                           const float* __restrict__ bias,
                                           unsigned short* __restrict__ uBt,
                                           float* __restrict__ whb) {
    int bx = blockIdx.x;
    if (bx < 256) {
        const int NS = NSTEP * BSLOT;  // 131072 slots
        for (int s = bx * 256 + threadIdx.x; s < NS; s += 256 * 256) {
            int t   = s >> 12;
            int rem = s & 4095;
            int r   = rem >> 3;
            int c   = (rem & 7) ^ (r & 7);
            const float* src = U + (size_t)r * FEAT + t * 64 + c * 8;
            float4 v0 = *(const float4*)src;
            float4 v1 = *(const float4*)(src + 4);
            ushort4 o0, o1;
            o0.x = f2bf(v0.x); o0.y = f2bf(v0.y); o0.z = f2bf(v0.z); o0.w = f2bf(v0.w);
            o1.x = f2bf(v1.x); o1.y = f2bf(v1.y); o1.z = f2bf(v1.z); o1.w = f2bf(v1.w);
            ((ushort4*)uBt)[s * 2]     = o0;
            ((ushort4*)uBt)[s * 2 + 1] = o1;
        }
    } else {
        int bid = bx - 256;                  // 0..8191
        int b = bid >> 7;                    // 0..63
        int k = (bid & 127) * 4 + (threadIdx.x >> 6);
        int lane = threadIdx.x & 63;
        const float* hrow = hidden + (size_t)b * HID;
        const float* wrow = W + (size_t)k * HID;
        float acc = 0.f;
        #pragma unroll 4
        for (int h = lane; h < HID; h += 64) acc += hrow[h] * wrow[h];
        #pragma unroll
        for (int off = 32; off > 0; off >>= 1) acc += __shfl_down(acc, off, 64);
        if (lane == 0) whb[b * KDIM + k] = acc + bias[k];
    }
}

// ---------------------------------------------------------------------------
// k2n: bf16 MFMA GEMM, full-N strip per block + fused tanh/dot(w) epilogue.
// Tile M=128 x N=512 (ALL of K-dim), BK=64, 512 thr = 8 waves (2m x 4n),
// wave-tile 64x128 (4x8 16x16x32 MFMAs per kk, kk in {0,1}).
// PIPELINED (T3-minimum): B double-buffered; B(t+1) GLL16 + A(t+1) f32 loads
// are issued BEFORE compute(t), so the barrier's vmcnt(0) drain finds loads
// already landed. A stays single-buffered: its next tile rides in registers
// through compute(t) and is cvt+ds_written after the barrier (2nd cheap
// lgkm-only barrier). B source is the k0n-packed tile: every GLL16 is a
// contiguous 1 KB burst (vs 8 scattered 128B transactions before).
// Swizzle baked into the pack; reads use the proven XOR pattern (0 conflicts).
// LDS 146 KB -> 1 block/CU, grid = 256 = #CUs.
// ---------------------------------------------------------------------------
__global__ __launch_bounds__(512, 2) void k2n(const float* __restrict__ feats,
                                              const unsigned short* __restrict__ uBt,
                                              const float* __restrict__ whb,
                                              const float* __restrict__ wvec,
                                              float* __restrict__ energies) {
    __shared__ __align__(16) unsigned short As[128 * 64];     // 16 KB
    __shared__ __align__(16) unsigned short Bs[2][512 * 64];  // 128 KB
    __shared__ float sums[4][128];                            // 2 KB

    const int tid  = threadIdx.x;
    const int wave = tid >> 6;
    const int lane = tid & 63;
    const int row0 = blockIdx.x * 128;
    const int wm = wave >> 2;            // 0..1 (M)
    const int wn = wave & 3;             // 0..3 (N)
    const int col = lane & 15, quad = lane >> 4;

    // ---- A staging map: thread owns slots {tid, tid+512} of 1024 16B slots
    const int sr = tid >> 3;                  // row of slot tid (0..63)
    const int sc = (tid & 7) ^ (sr & 7);      // swizzled chunk
    const float* gA = feats + (size_t)(row0 + sr) * FEAT + sc * 8;
    unsigned short* lA0 = As + tid * 8;             // slot tid
    unsigned short* lA1 = As + (tid + 512) * 8;     // slot tid+512 (row sr+64)

    // ---- B staging: 8 GLL16/thread/iter from the packed tile (contiguous)
    const unsigned short* gB = uBt + (size_t)(wave * 512 + lane) * 8;

    floatx4 acc[4][8];
    #pragma unroll
    for (int i = 0; i < 4; ++i)
        #pragma unroll
        for (int j = 0; j < 8; ++j) acc[i][j] = (floatx4){0.f, 0.f, 0.f, 0.f};

    // ---- prologue: A(0) regs, B(0) GLL16 -> Bs[0], cvt+write A(0), drain
    float4 a0 = *(const float4*)(gA);
    float4 a1 = *(const float4*)(gA + 4);
    float4 a2 = *(const float4*)(gA + (size_t)64 * FEAT);
    float4 a3 = *(const float4*)(gA + (size_t)64 * FEAT + 4);
    gA += 64;
    #pragma unroll
    for (int g = 0; g < 8; ++g)
        GLL16(gB + g * 512, &Bs[0][(wave * 512 + g * 64) * 8]);
    {
        short8 w0, w1;
        w0[0] = f2bf(a0.x); w0[1] = f2bf(a0.y); w0[2] = f2bf(a0.z); w0[3] = f2bf(a0.w);
        w0[4] = f2bf(a1.x); w0[5] = f2bf(a1.y); w0[6] = f2bf(a1.z); w0[7] = f2bf(a1.w);
        w1[0] = f2bf(a2.x); w1[1] = f2bf(a2.y); w1[2] = f2bf(a2.z); w1[3] = f2bf(a2.w);
        w1[4] = f2bf(a3.x); w1[5] = f2bf(a3.y); w1[6] = f2bf(a3.z); w1[7] = f2bf(a3.w);
        *(short8*)lA0 = w0;
        *(short8*)lA1 = w1;
    }
    __syncthreads();   // tile 0 ready (one full-latency drain, prologue only)

    int nb = 0;
    for (int t = 0; t < NSTEP; ++t) {
        // ---- issue-early: A(t+1) f32 -> regs, B(t+1) GLL16 -> Bs[nb^1].
        // These fly for the whole compute phase below.
        if (t < NSTEP - 1) {
            a0 = *(const float4*)(gA);
            a1 = *(const float4*)(gA + 4);
            a2 = *(const float4*)(gA + (size_t)64 * FEAT);
            a3 = *(const float4*)(gA + (size_t)64 * FEAT + 4);
            gA += 64;
            const unsigned short* gb = gB + (size_t)(t + 1) * BTILE;
            unsigned short* lb = &Bs[nb ^ 1][(wave * 512) * 8];
            #pragma unroll
            for (int g = 0; g < 8; ++g)
                GLL16(gb + g * 512, lb + g * 512);
        }

        // ---- compute on As, Bs[nb]
        #pragma unroll
        for (int kk = 0; kk < 2; ++kk) {
            const int sw = ((kk * 4 + quad) ^ (col & 7)) * 8;
            short8 af[4], bf[8];
            #pragma unroll
            for (int i = 0; i < 4; ++i)
                af[i] = *(const short8*)&As[(wm * 64 + i * 16 + col) * 64 + sw];
            #pragma unroll
            for (int j = 0; j < 8; ++j)
                bf[j] = *(const short8*)&Bs[nb][(wn * 128 + j * 16 + col) * 64 + sw];
            #pragma unroll
            for (int i = 0; i < 4; ++i)
                #pragma unroll
                for (int j = 0; j < 8; ++j)
                    acc[i][j] = __builtin_amdgcn_mfma_f32_16x16x32_bf16(
                        af[i], bf[j], acc[i][j], 0, 0, 0);
        }
        __syncthreads();   // As(t)/Bs[nb] reads done; B(t+1)+A-regs drained (landed)

        if (t < NSTEP - 1) {
            short8 w0, w1;
            w0[0] = f2bf(a0.x); w0[1] = f2bf(a0.y); w0[2] = f2bf(a0.z); w0[3] = f2bf(a0.w);
            w0[4] = f2bf(a1.x); w0[5] = f2bf(a1.y); w0[6] = f2bf(a1.z); w0[7] = f2bf(a1.w);
            w1[0] = f2bf(a2.x); w1[1] = f2bf(a2.y); w1[2] = f2bf(a2.z); w1[3] = f2bf(a2.w);
            w1[4] = f2bf(a3.x); w1[5] = f2bf(a3.y); w1[6] = f2bf(a3.z); w1[7] = f2bf(a3.w);
            *(short8*)lA0 = w0;
            *(short8*)lA1 = w1;
            __syncthreads();   // A(t+1) visible (lgkm-only, cheap)
        }
        nb ^= 1;
    }

    // Epilogue. C/D layout: col = lane&15 (n/k-dim), row = quad*4 + reg (m).
    const int b = row0 >> 9;   // 128-row block stays within one batch (T=512)
    float wk[8], hk[8];
    #pragma unroll
    for (int j = 0; j < 8; ++j) {
        int k = wn * 128 + j * 16 + col;
        wk[j] = wvec[k];
        hk[j] = whb[b * KDIM + k];
    }
    #pragma unroll
    for (int i = 0; i < 4; ++i) {
        #pragma unroll
        for (int r = 0; r < 4; ++r) {
            float s = 0.f;
            #pragma unroll
            for (int j = 0; j < 8; ++j)
                s += tanhf(acc[i][j][r] + hk[j]) * wk[j];
            #pragma unroll
            for (int off = 8; off > 0; off >>= 1)
                s += __shfl_down(s, off, 16);
            if (col == 0)
                sums[wn][wm * 64 + i * 16 + quad * 4 + r] = s;
        }
    }
    __syncthreads();
    if (tid < 128)
        energies[row0 + tid] =
            sums[0][tid] + sums[1][tid] + sums[2][tid] + sums[3][tid];
}

// ---------------------------------------------------------------------------
// k3n: softmax over T per batch (energies are complete — no partial sum)
// ---------------------------------------------------------------------------
__global__ __launch_bounds__(512) void k3n(const float* __restrict__ energies,
                                           float* __restrict__ wout) {
    int b = blockIdx.x;
    int t = threadIdx.x;
    float e = energies[b * TDIM + t];

    __shared__ float sm[512];
    sm[t] = e;
    __syncthreads();
    #pragma unroll
    for (int s = 256; s > 0; s >>= 1) {
        if (t < s) sm[t] = fmaxf(sm[t], sm[t + s]);
        __syncthreads();
    }
    float m = sm[0];
    __syncthreads();
    float ex = __expf(e - m);
    sm[t] = ex;
    __syncthreads();
    #pragma unroll
    for (int s = 256; s > 0; s >>= 1) {
        if (t < s) sm[t] += sm[t + s];
        __syncthreads();
    }
    float inv = 1.f / sm[0];
    wout[b * TDIM + t] = ex * inv;
}

// ---------------------------------------------------------------------------
// k4n: T-chunked weighted pooling straight from f32 feats.
// grid (TCH=16, BATCH); block covers FEAT=2048 (8 f32/thread), TCLEN=32 steps.
// ---------------------------------------------------------------------------
__global__ __launch_bounds__(256) void k4n(const float* __restrict__ feats,
                                           const float* __restrict__ weights,
                                           float* __restrict__ partial4) {
    int b  = blockIdx.y;
    int t0 = blockIdx.x * TCLEN;
    int f8 = threadIdx.x * 8;
    __shared__ float wsm[TCLEN];
    if (threadIdx.x < TCLEN) wsm[threadIdx.x] = weights[b * TDIM + t0 + threadIdx.x];
    __syncthreads();

    const float* fp = feats + ((size_t)b * TDIM + t0) * FEAT + f8;
    float a[8];
    #pragma unroll
    for (int e = 0; e < 8; ++e) a[e] = 0.f;
    #pragma unroll 4
    for (int t = 0; t < TCLEN; ++t) {
        float4 v0 = *(const float4*)(fp + (size_t)t * FEAT);
        float4 v1 = *(const float4*)(fp + (size_t)t * FEAT + 4);
        float w = wsm[t];
        a[0] += v0.x * w; a[1] += v0.y * w; a[2] += v0.z * w; a[3] += v0.w * w;
        a[4] += v1.x * w; a[5] += v1.y * w; a[6] += v1.z * w; a[7] += v1.w * w;
    }
    float* op = partial4 + ((size_t)blockIdx.x * BATCH + b) * FEAT + f8;
    float4 o0 = {a[0], a[1], a[2], a[3]};
    float4 o1 = {a[4], a[5], a[6], a[7]};
    *(float4*)op = o0;
    *(float4*)(op + 4) = o1;
}

__global__ __launch_bounds__(256) void k5_reduce(const float* __restrict__ partial4,
                                                 float* __restrict__ out) {
    int i4 = blockIdx.x * 256 + threadIdx.x;  // float4 index into B*FEAT
    float4 s = ((const float4*)partial4)[i4];
    #pragma unroll
    for (int c = 1; c < TCH; ++c) {
        float4 v = ((const float4*)partial4)[(size_t)c * (BATCH * FEAT / 4) + i4];
        s.x += v.x; s.y += v.y; s.z += v.z; s.w += v.w;
    }
    ((float4*)out)[i4] = s;
}

// ---------------------------------------------------------------------------
// Fallback-path kernels (tiny ws): original k1 + f32 tile GEMM + direct pool
// ---------------------------------------------------------------------------
#define BM 128
#define BN 128
#define BF 16
#define LDSPAD 4

__global__ __launch_bounds__(256) void k1_whb(const float* __restrict__ hidden,
                                              const float* __restrict__ W,
                                              const float* __restrict__ bias,
                                              float* __restrict__ whb) {
    int b = blockIdx.y;
    int k = blockIdx.x * 4 + (threadIdx.x >> 6);
    int lane = threadIdx.x & 63;
    const float* hrow = hidden + (size_t)b * HID;
    const float* wrow = W + (size_t)k * HID;
    float acc = 0.f;
    #pragma unroll 4
    for (int h = lane; h < HID; h += 64) acc += hrow[h] * wrow[h];
    #pragma unroll
    for (int off = 32; off > 0; off >>= 1) acc += __shfl_down(acc, off, 64);
    if (lane == 0) whb[b * KDIM + k] = acc + bias[k];
}

__global__ __launch_bounds__(256) void k2_energy(const float* __restrict__ feats,
                                                 const float* __restrict__ U,
                                                 const float* __restrict__ whb,
                                                 const float* __restrict__ wvec,
                                                 float* __restrict__ partial) {
    __shared__ __align__(16) float As[BF][BM + LDSPAD];
    __shared__ __align__(16) float Us[BF][BN + LDSPAD];

    const int row0 = blockIdx.x * BM;
    const int k0   = blockIdx.y * BN;
    const int tid  = threadIdx.x;
    const int tx   = tid & 15;
    const int ty   = tid >> 4;

    float acc[8][8];
    #pragma unroll
    for (int i = 0; i < 8; ++i)
        #pragma unroll
        for (int j = 0; j < 8; ++j) acc[i][j] = 0.f;

    for (int f0 = 0; f0 < FEAT; f0 += BF) {
        #pragma unroll
        for (int l = 0; l < 2; ++l) {
            int li = tid + l * 256;
            int r  = li >> 2;
            int c4 = (li & 3) * 4;
            float4 av = *(const float4*)(feats + (size_t)(row0 + r) * FEAT + f0 + c4);
            float4 uv = *(const float4*)(U     + (size_t)(k0   + r) * FEAT + f0 + c4);
            As[c4 + 0][r] = av.x; As[c4 + 1][r] = av.y;
            As[c4 + 2][r] = av.z; As[c4 + 3][r] = av.w;
            Us[c4 + 0][r] = uv.x; Us[c4 + 1][r] = uv.y;
            Us[c4 + 2][r] = uv.z; Us[c4 + 3][r] = uv.w;
        }
        __syncthreads();
        #pragma unroll
        for (int kf = 0; kf < BF; ++kf) {
            float4 a0 = *(const float4*)&As[kf][ty * 8];
            float4 a1 = *(const float4*)&As[kf][ty * 8 + 4];
            float4 u0 = *(const float4*)&Us[kf][tx * 8];
            float4 u1 = *(const float4*)&Us[kf][tx * 8 + 4];
            float a[8] = {a0.x, a0.y, a0.z, a0.w, a1.x, a1.y, a1.z, a1.w};
            float u[8] = {u0.x, u0.y, u0.z, u0.w, u1.x, u1.y, u1.z, u1.w};
            #pragma unroll
            for (int i = 0; i < 8; ++i)
                #pragma unroll
                for (int j = 0; j < 8; ++j) acc[i][j] += a[i] * u[j];
        }
        __syncthreads();
    }

    const int b = row0 >> 9;
    float psum[8];
    #pragma unroll
    for (int i = 0; i < 8; ++i) {
        float s = 0.f;
        #pragma unroll
        for (int j = 0; j < 8; ++j) {
            int k = k0 + tx * 8 + j;
            s += tanhf(acc[i][j] + whb[b * KDIM + k]) * wvec[k];
        }
        psum[i] = s;
    }
    #pragma unroll
    for (int off = 8; off > 0; off >>= 1)
        #pragma unroll
        for (int i = 0; i < 8; ++i) psum[i] += __shfl_down(psum[i], off, 16);

    if (tx == 0) {
        int c = blockIdx.y;
        #pragma unroll
        for (int i = 0; i < 8; ++i)
            partial[c * MROWS + row0 + ty * 8 + i] = psum[i];
    }
}

__global__ __launch_bounds__(512) void k3_softmax(const float* __restrict__ partial,
                                                  float* __restrict__ wout) {
    int b = blockIdx.x;
    int t = threadIdx.x;
    float e = 0.f;
    #pragma unroll
    for (int c = 0; c < 4; ++c) e += partial[c * MROWS + b * TDIM + t];

    __shared__ float sm[512];
    sm[t] = e;
    __syncthreads();
    #pragma unroll
    for (int s = 256; s > 0; s >>= 1) {
        if (t < s) sm[t] = fmaxf(sm[t], sm[t + s]);
        __syncthreads();
    }
    float m = sm[0];
    __syncthreads();
    float ex = __expf(e - m);
    sm[t] = ex;
    __syncthreads();
    #pragma unroll
    for (int s = 256; s > 0; s >>= 1) {
        if (t < s) sm[t] += sm[t + s];
        __syncthreads();
    }
    float inv = 1.f / sm[0];
    wout[b * TDIM + t] = ex * inv;
}

__global__ __launch_bounds__(256) void k4_direct(const float* __restrict__ feats,
                                                 const float* __restrict__ weights,
                                                 float* __restrict__ out) {
    int b = blockIdx.y;
    int f4 = (blockIdx.x * 256 + threadIdx.x) * 4;
    __shared__ float wsm[TDIM];
    wsm[threadIdx.x]       = weights[b * TDIM + threadIdx.x];
    wsm[threadIdx.x + 256] = weights[b * TDIM + 256 + threadIdx.x];
    __syncthreads();

    const float* fp = feats + (size_t)b * TDIM * FEAT + f4;
    float ax = 0.f, ay = 0.f, az = 0.f, aw = 0.f;
    for (int t = 0; t < TDIM; ++t) {
        float4 v = *(const float4*)(fp + (size_t)t * FEAT);
        float w = wsm[t];
        ax += v.x * w; ay += v.y * w; az += v.z * w; aw += v.w * w;
    }
    float4 o = {ax, ay, az, aw};
    *(float4*)(out + (size_t)b * FEAT + f4) = o;
}

// ---------------------------------------------------------------------------
// Launch. d_out: [0, B*FEAT) attn_feats, [B*FEAT, +B*T) weights.
// d_out staging: Whb in weights region (dead after k2n); energies in attn
// region (dead after k3n). d_ws: packed bf16 U tiles (2 MB) + pooling
// partials (8 MB). Branch on host-constant ws_size (graph-safe).
// ---------------------------------------------------------------------------
extern "C" void kernel_launch(void* const* d_in, const int* in_sizes, int n_in,
                              void* d_out, int out_size, void* d_ws, size_t ws_size,
                              hipStream_t stream) {
    const float* hidden = (const float*)d_in[0];
    const float* feats  = (const float*)d_in[1];
    const float* W      = (const float*)d_in[2];
    const float* U      = (const float*)d_in[3];
    const float* bias   = (const float*)d_in[4];
    const float* wvec   = (const float*)d_in[5];

    float* out         = (float*)d_out;
    float* attn_out    = out;
    float* weights_out = out + (size_t)BATCH * FEAT;
    float* whb         = weights_out;  // staged (dead after k2n)
    float* energies    = attn_out;     // staged (dead after k3n)

    const size_t uN        = (size_t)KDIM * FEAT;
    const size_t uBytes    = uN * sizeof(unsigned short);
    const size_t poolBytes = (size_t)TCH * BATCH * FEAT * sizeof(float);
    const bool fast = ws_size >= uBytes + poolBytes;

    if (fast) {
        unsigned short* uBt = (unsigned short*)d_ws;
        float* pool4 = (float*)((char*)d_ws + uBytes);
        k0n<<<dim3(256 + 8192), 256, 0, stream>>>(U, hidden, W, bias, uBt, whb);
        k2n<<<dim3(MROWS / 128), 512, 0, stream>>>(feats, uBt, whb, wvec, energies);
        k3n<<<dim3(BATCH), 512, 0, stream>>>(energies, weights_out);
        k4n<<<dim3(TCH, BATCH), 256, 0, stream>>>(feats, weights_out, pool4);
        k5_reduce<<<dim3(BATCH * FEAT / 4 / 256), 256, 0, stream>>>(pool4, attn_out);
    } else {
        k1_whb<<<dim3(KDIM / 4, BATCH), 256, 0, stream>>>(hidden, W, bias, whb);
        k2_energy<<<dim3(MROWS / 128, KDIM / 128), 256, 0, stream>>>(
            feats, U, whb, wvec, energies);
        k3_softmax<<<dim3(BATCH), 512, 0, stream>>>(energies, weights_out);
        k4_direct<<<dim3(FEAT / 1024, BATCH), 256, 0, stream>>>(
            feats, weights_out, attn_out);
    }
}

// Round 4
// 489.695 us; speedup vs baseline: 1.0202x; 1.0202x over previous
//
#include <hip/hip_runtime.h>
#include <math.h>

// Problem constants (from reference)
#define BATCH 64
#define TDIM 512
#define FEAT 2048
#define HID 1024
#define KDIM 512
#define MROWS (BATCH * TDIM)  // 32768 flat feats rows
#define TCH 16                // k4 time-chunks
#define TCLEN (TDIM / TCH)    // 32 t per chunk

#define NSTEP (FEAT / 64)     // 32 K-steps in the GEMM
#define BSLOT (KDIM * 8)      // 4096 16B-slots per packed B tile
#define BTILE (BSLOT * 8)     // 32768 bf16 elements per packed B tile

typedef __attribute__((ext_vector_type(8))) short short8;
typedef __attribute__((ext_vector_type(4))) float floatx4;

// global -> LDS direct DMA, 16B per lane; LDS dest is wave-uniform base,
// lane i lands at base + i*16 (per-lane LDS address is NOT honored).
#define GLL16(g, l)                                                     \
    __builtin_amdgcn_global_load_lds(                                   \
        (const __attribute__((address_space(1))) void*)(g),             \
        (__attribute__((address_space(3))) void*)(l), 16, 0, 0)

// Counted waits (T4): compiler-invisible cross-wave ordering. sched_barrier
// pins compiler motion around them (learn_hip rule #18).
#define VMWAIT(N) asm volatile("s_waitcnt vmcnt(" #N ")" ::: "memory")
#define LGKM0     asm volatile("s_waitcnt lgkmcnt(0)" ::: "memory")
#define SCHEDB    __builtin_amdgcn_sched_barrier(0)
#define SBAR      __builtin_amdgcn_s_barrier()

// ---------------------------------------------------------------------------
// f32 -> bf16 (round-to-nearest-even)
// ---------------------------------------------------------------------------
__device__ __forceinline__ unsigned short f2bf(float x) {
    unsigned int u = __float_as_uint(x);
    u += 0x7FFFu + ((u >> 16) & 1u);
    return (unsigned short)(u >> 16);
}

// ---------------------------------------------------------------------------
// k0n: blocks [0,256): PACK U f32 -> bf16 in K-step-tile-major, pre-swizzled
//      order: slot s = t*4096 + r*8 + ((c)^(r&7)) holds U[r][t*64+c*8..+8].
//      Each 64 KB tile is then a contiguous sequential GLL16 source in k2n.
//      blocks [256,8448): Whb[b,k] = hidden[b]·W[k] + bias[k]
// ---------------------------------------------------------------------------
__global__ __launch_bounds__(256) void k0n(const float* __restrict__ U,
                                           const float* __restrict__ hidden,
                                           const float* __restrict__ W,
                                           const float* __restrict__ bias,
                                           unsigned short* __restrict__ uBt,
                                           float* __restrict__ whb) {
    int bx = blockIdx.x;
    if (bx < 256) {
        const int NS = NSTEP * BSLOT;  // 131072 slots
        for (int s = bx * 256 + threadIdx.x; s < NS; s += 256 * 256) {
            int t   = s >> 12;
            int rem = s & 4095;
            int r   = rem >> 3;
            int c   = (rem & 7) ^ (r & 7);
            const float* src = U + (size_t)r * FEAT + t * 64 + c * 8;
            float4 v0 = *(const float4*)src;
            float4 v1 = *(const float4*)(src + 4);
            ushort4 o0, o1;
            o0.x = f2bf(v0.x); o0.y = f2bf(v0.y); o0.z = f2bf(v0.z); o0.w = f2bf(v0.w);
            o1.x = f2bf(v1.x); o1.y = f2bf(v1.y); o1.z = f2bf(v1.z); o1.w = f2bf(v1.w);
            ((ushort4*)uBt)[s * 2]     = o0;
            ((ushort4*)uBt)[s * 2 + 1] = o1;
        }
    } else {
        int bid = bx - 256;                  // 0..8191
        int b = bid >> 7;                    // 0..63
        int k = (bid & 127) * 4 + (threadIdx.x >> 6);
        int lane = threadIdx.x & 63;
        const float* hrow = hidden + (size_t)b * HID;
        const float* wrow = W + (size_t)k * HID;
        float acc = 0.f;
        #pragma unroll 4
        for (int h = lane; h < HID; h += 64) acc += hrow[h] * wrow[h];
        #pragma unroll
        for (int off = 32; off > 0; off >>= 1) acc += __shfl_down(acc, off, 64);
        if (lane == 0) whb[b * KDIM + k] = acc + bias[k];
    }
}

// ---------------------------------------------------------------------------
// k2n: bf16 MFMA GEMM, full-N strip per block + fused tanh/dot(w) epilogue.
// Tile M=128 x N=512 (ALL of K-dim), BK=64, 512 thr = 8 waves (2m x 4n),
// wave-tile 64x128 (4x8 16x16x32 MFMAs per kk, kk in {0,1}).
//
// COUNTED-VMCNT SCHEDULE (T3+T4, raw s_barrier — no vmcnt(0) in main loop):
//   per iter t: compute(As[c],Bs[c]) ; vmcnt(8) [A(t+1) regs landed, B(t+1)
//   GLL16s keep flying] ; cvt+ds_write A(t+1)->As[n] ; issue A(t+2) f32 ;
//   vmcnt(4) [B(t+1) landed, A(t+2) flying] ; lgkm0 ; s_barrier ;
//   issue B(t+2) GLL16 -> Bs[c] (just freed).
// Every load gets a full compute phase (~2.5k cyc) to land. A and B both
// double-buffered: LDS = 2*16 + 2*64 = 160 KiB exactly; epilogue 'sums'
// aliases the dead As buffer. 1 block/CU, grid = 256 = #CUs.
// B source is the k0n-packed tile: every GLL16 is a contiguous 1 KB burst.
// Swizzle baked into pack; reads use proven XOR pattern (0 conflicts).
// ---------------------------------------------------------------------------
__global__ __launch_bounds__(512, 2) void k2n(const float* __restrict__ feats,
                                              const unsigned short* __restrict__ uBt,
                                              const float* __restrict__ whb,
                                              const float* __restrict__ wvec,
                                              float* __restrict__ energies) {
    __shared__ __align__(16) unsigned short As[2][128 * 64];  // 32 KB
    __shared__ __align__(16) unsigned short Bs[2][512 * 64];  // 128 KB

    const int tid  = threadIdx.x;
    const int wave = tid >> 6;
    const int lane = tid & 63;
    const int row0 = blockIdx.x * 128;
    const int wm = wave >> 2;            // 0..1 (M)
    const int wn = wave & 3;             // 0..3 (N)
    const int col = lane & 15, quad = lane >> 4;

    // ---- A staging map: thread owns slots {tid, tid+512} of 1024 16B slots
    const int sr = tid >> 3;                  // row of slot tid (0..63)
    const int sc = (tid & 7) ^ (sr & 7);      // swizzled chunk
    const float* gA = feats + (size_t)(row0 + sr) * FEAT + sc * 8;

    // ---- B staging: 8 GLL16/thread/iter from the packed tile (contiguous)
    const unsigned short* gB = uBt + (size_t)(wave * 512 + lane) * 8;

    floatx4 acc[4][8];
    #pragma unroll
    for (int i = 0; i < 4; ++i)
        #pragma unroll
        for (int j = 0; j < 8; ++j) acc[i][j] = (floatx4){0.f, 0.f, 0.f, 0.f};

    float4 a0, a1, a2, a3;

    // issue A(t') f32 row-pair loads into a-regs (4 vmem events)
    #define LOAD_A()                                           \
        do {                                                   \
            a0 = *(const float4*)(gA);                         \
            a1 = *(const float4*)(gA + 4);                     \
            a2 = *(const float4*)(gA + (size_t)64 * FEAT);     \
            a3 = *(const float4*)(gA + (size_t)64 * FEAT + 4); \
            gA += 64;                                          \
        } while (0)

    // cvt a-regs -> swizzled bf16 ds_write into As[buf]
    #define CVT_WRITE_A(buf)                                                       \
        do {                                                                       \
            short8 w0, w1;                                                         \
            w0[0] = f2bf(a0.x); w0[1] = f2bf(a0.y);                                \
            w0[2] = f2bf(a0.z); w0[3] = f2bf(a0.w);                                \
            w0[4] = f2bf(a1.x); w0[5] = f2bf(a1.y);                                \
            w0[6] = f2bf(a1.z); w0[7] = f2bf(a1.w);                                \
            w1[0] = f2bf(a2.x); w1[1] = f2bf(a2.y);                                \
            w1[2] = f2bf(a2.z); w1[3] = f2bf(a2.w);                                \
            w1[4] = f2bf(a3.x); w1[5] = f2bf(a3.y);                                \
            w1[6] = f2bf(a3.z); w1[7] = f2bf(a3.w);                                \
            *(short8*)&As[buf][tid * 8]         = w0;                              \
            *(short8*)&As[buf][(tid + 512) * 8] = w1;                              \
        } while (0)

    // issue 8 GLL16 for tile tt into Bs[buf] (8 vmem events)
    #define ISSUE_B(tt, buf)                                               \
        do {                                                               \
            const unsigned short* gb = gB + (size_t)(tt) * BTILE;          \
            unsigned short* lb = &Bs[buf][(wave * 512) * 8];               \
            _Pragma("unroll")                                              \
            for (int g = 0; g < 8; ++g) GLL16(gb + g * 512, lb + g * 512); \
        } while (0)

    // ---- prologue --------------------------------------------------------
    LOAD_A();            // A(0): queue [A0 x4]
    ISSUE_B(0, 0);       // queue [A0 x4, B0 x8]
    VMWAIT(8); SCHEDB;   // A(0) landed
    CVT_WRITE_A(0);
    LOAD_A();            // A(1): queue [B0 x8, A1 x4]
    VMWAIT(4); SCHEDB;   // B(0) landed (A(1) flying)
    LGKM0; SCHEDB;       // As[0] writes visible
    SBAR; SCHEDB;
    ISSUE_B(1, 1);       // queue [A1 x4, B1 x8]

    // ---- main loop: ONE barrier per K-step, no vmcnt(0) ------------------
    for (int t = 0; t < NSTEP; ++t) {
        const int cur = t & 1, nxt = cur ^ 1;

        #pragma unroll
        for (int kk = 0; kk < 2; ++kk) {
            const int sw = ((kk * 4 + quad) ^ (col & 7)) * 8;
            short8 af[4], bf[8];
            #pragma unroll
            for (int i = 0; i < 4; ++i)
                af[i] = *(const short8*)&As[cur][(wm * 64 + i * 16 + col) * 64 + sw];
            #pragma unroll
            for (int j = 0; j < 8; ++j)
                bf[j] = *(const short8*)&Bs[cur][(wn * 128 + j * 16 + col) * 64 + sw];
            #pragma unroll
            for (int i = 0; i < 4; ++i)
                #pragma unroll
                for (int j = 0; j < 8; ++j)
                    acc[i][j] = __builtin_amdgcn_mfma_f32_16x16x32_bf16(
                        af[i], bf[j], acc[i][j], 0, 0, 0);
        }

        if (t < NSTEP - 1) {
            VMWAIT(8); SCHEDB;       // A(t+1) landed; B(t+1) may still fly
            CVT_WRITE_A(nxt);        // disjoint from As[cur] being read
            if (t < NSTEP - 2) {
                LOAD_A();            // A(t+2): queue [B(t+1) x8, A(t+2) x4]
                VMWAIT(4); SCHEDB;   // B(t+1) landed (A(t+2) flying)
            } else {
                VMWAIT(0); SCHEDB;   // last B has no younger loads behind it
            }
            LGKM0; SCHEDB;           // As[nxt] ds_writes visible
            SBAR; SCHEDB;            // all waves: As[nxt], Bs[nxt] ready
            if (t < NSTEP - 2)
                ISSUE_B(t + 2, cur); // reload just-freed Bs[cur]
        }
    }

    __syncthreads();  // all compute(31) LDS reads done; As now dead

    // Epilogue. sums aliases the dead As buffer (saves 2 KB LDS overflow).
    float (*sums)[128] = (float (*)[128])As;
    const int b = row0 >> 9;   // 128-row block stays within one batch (T=512)
    float wk[8], hk[8];
    #pragma unroll
    for (int j = 0; j < 8; ++j) {
        int k = wn * 128 + j * 16 + col;
        wk[j] = wvec[k];
        hk[j] = whb[b * KDIM + k];
    }
    #pragma unroll
    for (int i = 0; i < 4; ++i) {
        #pragma unroll
        for (int r = 0; r < 4; ++r) {
            float s = 0.f;
            #pragma unroll
            for (int j = 0; j < 8; ++j)
                s += tanhf(acc[i][j][r] + hk[j]) * wk[j];
            #pragma unroll
            for (int off = 8; off > 0; off >>= 1)
                s += __shfl_down(s, off, 16);
            if (col == 0)
                sums[wn][wm * 64 + i * 16 + quad * 4 + r] = s;
        }
    }
    __syncthreads();
    if (tid < 128)
        energies[row0 + tid] =
            sums[0][tid] + sums[1][tid] + sums[2][tid] + sums[3][tid];

    #undef LOAD_A
    #undef CVT_WRITE_A
    #undef ISSUE_B
}

// ---------------------------------------------------------------------------
// k3n: softmax over T per batch (energies are complete — no partial sum)
// ---------------------------------------------------------------------------
__global__ __launch_bounds__(512) void k3n(const float* __restrict__ energies,
                                           float* __restrict__ wout) {
    int b = blockIdx.x;
    int t = threadIdx.x;
    float e = energies[b * TDIM + t];

    __shared__ float sm[512];
    sm[t] = e;
    __syncthreads();
    #pragma unroll
    for (int s = 256; s > 0; s >>= 1) {
        if (t < s) sm[t] = fmaxf(sm[t], sm[t + s]);
        __syncthreads();
    }
    float m = sm[0];
    __syncthreads();
    float ex = __expf(e - m);
    sm[t] = ex;
    __syncthreads();
    #pragma unroll
    for (int s = 256; s > 0; s >>= 1) {
        if (t < s) sm[t] += sm[t + s];
        __syncthreads();
    }
    float inv = 1.f / sm[0];
    wout[b * TDIM + t] = ex * inv;
}

// ---------------------------------------------------------------------------
// k4n: T-chunked weighted pooling straight from f32 feats.
// grid (TCH=16, BATCH); block covers FEAT=2048 (8 f32/thread), TCLEN=32 steps.
// ---------------------------------------------------------------------------
__global__ __launch_bounds__(256) void k4n(const float* __restrict__ feats,
                                           const float* __restrict__ weights,
                                           float* __restrict__ partial4) {
    int b  = blockIdx.y;
    int t0 = blockIdx.x * TCLEN;
    int f8 = threadIdx.x * 8;
    __shared__ float wsm[TCLEN];
    if (threadIdx.x < TCLEN) wsm[threadIdx.x] = weights[b * TDIM + t0 + threadIdx.x];
    __syncthreads();

    const float* fp = feats + ((size_t)b * TDIM + t0) * FEAT + f8;
    float a[8];
    #pragma unroll
    for (int e = 0; e < 8; ++e) a[e] = 0.f;
    #pragma unroll 4
    for (int t = 0; t < TCLEN; ++t) {
        float4 v0 = *(const float4*)(fp + (size_t)t * FEAT);
        float4 v1 = *(const float4*)(fp + (size_t)t * FEAT + 4);
        float w = wsm[t];
        a[0] += v0.x * w; a[1] += v0.y * w; a[2] += v0.z * w; a[3] += v0.w * w;
        a[4] += v1.x * w; a[5] += v1.y * w; a[6] += v1.z * w; a[7] += v1.w * w;
    }
    float* op = partial4 + ((size_t)blockIdx.x * BATCH + b) * FEAT + f8;
    float4 o0 = {a[0], a[1], a[2], a[3]};
    float4 o1 = {a[4], a[5], a[6], a[7]};
    *(float4*)op = o0;
    *(float4*)(op + 4) = o1;
}

__global__ __launch_bounds__(256) void k5_reduce(const float* __restrict__ partial4,
                                                 float* __restrict__ out) {
    int i4 = blockIdx.x * 256 + threadIdx.x;  // float4 index into B*FEAT
    float4 s = ((const float4*)partial4)[i4];
    #pragma unroll
    for (int c = 1; c < TCH; ++c) {
        float4 v = ((const float4*)partial4)[(size_t)c * (BATCH * FEAT / 4) + i4];
        s.x += v.x; s.y += v.y; s.z += v.z; s.w += v.w;
    }
    ((float4*)out)[i4] = s;
}

// ---------------------------------------------------------------------------
// Fallback-path kernels (tiny ws): original k1 + f32 tile GEMM + direct pool
// ---------------------------------------------------------------------------
#define BM 128
#define BN 128
#define BF 16
#define LDSPAD 4

__global__ __launch_bounds__(256) void k1_whb(const float* __restrict__ hidden,
                                              const float* __restrict__ W,
                                              const float* __restrict__ bias,
                                              float* __restrict__ whb) {
    int b = blockIdx.y;
    int k = blockIdx.x * 4 + (threadIdx.x >> 6);
    int lane = threadIdx.x & 63;
    const float* hrow = hidden + (size_t)b * HID;
    const float* wrow = W + (size_t)k * HID;
    float acc = 0.f;
    #pragma unroll 4
    for (int h = lane; h < HID; h += 64) acc += hrow[h] * wrow[h];
    #pragma unroll
    for (int off = 32; off > 0; off >>= 1) acc += __shfl_down(acc, off, 64);
    if (lane == 0) whb[b * KDIM + k] = acc + bias[k];
}

__global__ __launch_bounds__(256) void k2_energy(const float* __restrict__ feats,
                                                 const float* __restrict__ U,
                                                 const float* __restrict__ whb,
                                                 const float* __restrict__ wvec,
                                                 float* __restrict__ partial) {
    __shared__ __align__(16) float As[BF][BM + LDSPAD];
    __shared__ __align__(16) float Us[BF][BN + LDSPAD];

    const int row0 = blockIdx.x * BM;
    const int k0   = blockIdx.y * BN;
    const int tid  = threadIdx.x;
    const int tx   = tid & 15;
    const int ty   = tid >> 4;

    float acc[8][8];
    #pragma unroll
    for (int i = 0; i < 8; ++i)
        #pragma unroll
        for (int j = 0; j < 8; ++j) acc[i][j] = 0.f;

    for (int f0 = 0; f0 < FEAT; f0 += BF) {
        #pragma unroll
        for (int l = 0; l < 2; ++l) {
            int li = tid + l * 256;
            int r  = li >> 2;
            int c4 = (li & 3) * 4;
            float4 av = *(const float4*)(feats + (size_t)(row0 + r) * FEAT + f0 + c4);
            float4 uv = *(const float4*)(U     + (size_t)(k0   + r) * FEAT + f0 + c4);
            As[c4 + 0][r] = av.x; As[c4 + 1][r] = av.y;
            As[c4 + 2][r] = av.z; As[c4 + 3][r] = av.w;
            Us[c4 + 0][r] = uv.x; Us[c4 + 1][r] = uv.y;
            Us[c4 + 2][r] = uv.z; Us[c4 + 3][r] = uv.w;
        }
        __syncthreads();
        #pragma unroll
        for (int kf = 0; kf < BF; ++kf) {
            float4 a0 = *(const float4*)&As[kf][ty * 8];
            float4 a1 = *(const float4*)&As[kf][ty * 8 + 4];
            float4 u0 = *(const float4*)&Us[kf][tx * 8];
            float4 u1 = *(const float4*)&Us[kf][tx * 8 + 4];
            float a[8] = {a0.x, a0.y, a0.z, a0.w, a1.x, a1.y, a1.z, a1.w};
            float u[8] = {u0.x, u0.y, u0.z, u0.w, u1.x, u1.y, u1.z, u1.w};
            #pragma unroll
            for (int i = 0; i < 8; ++i)
                #pragma unroll
                for (int j = 0; j < 8; ++j) acc[i][j] += a[i] * u[j];
        }
        __syncthreads();
    }

    const int b = row0 >> 9;
    float psum[8];
    #pragma unroll
    for (int i = 0; i < 8; ++i) {
        float s = 0.f;
        #pragma unroll
        for (int j = 0; j < 8; ++j) {
            int k = k0 + tx * 8 + j;
            s += tanhf(acc[i][j] + whb[b * KDIM + k]) * wvec[k];
        }
        psum[i] = s;
    }
    #pragma unroll
    for (int off = 8; off > 0; off >>= 1)
        #pragma unroll
        for (int i = 0; i < 8; ++i) psum[i] += __shfl_down(psum[i], off, 16);

    if (tx == 0) {
        int c = blockIdx.y;
        #pragma unroll
        for (int i = 0; i < 8; ++i)
            partial[c * MROWS + row0 + ty * 8 + i] = psum[i];
    }
}

__global__ __launch_bounds__(512) void k3_softmax(const float* __restrict__ partial,
                                                  float* __restrict__ wout) {
    int b = blockIdx.x;
    int t = threadIdx.x;
    float e = 0.f;
    #pragma unroll
    for (int c = 0; c < 4; ++c) e += partial[c * MROWS + b * TDIM + t];

    __shared__ float sm[512];
    sm[t] = e;
    __syncthreads();
    #pragma unroll
    for (int s = 256; s > 0; s >>= 1) {
        if (t < s) sm[t] = fmaxf(sm[t], sm[t + s]);
        __syncthreads();
    }
    float m = sm[0];
    __syncthreads();
    float ex = __expf(e - m);
    sm[t] = ex;
    __syncthreads();
    #pragma unroll
    for (int s = 256; s > 0; s >>= 1) {
        if (t < s) sm[t] += sm[t + s];
        __syncthreads();
    }
    float inv = 1.f / sm[0];
    wout[b * TDIM + t] = ex * inv;
}

__global__ __launch_bounds__(256) void k4_direct(const float* __restrict__ feats,
                                                 const float* __restrict__ weights,
                                                 float* __restrict__ out) {
    int b = blockIdx.y;
    int f4 = (blockIdx.x * 256 + threadIdx.x) * 4;
    __shared__ float wsm[TDIM];
    wsm[threadIdx.x]       = weights[b * TDIM + threadIdx.x];
    wsm[threadIdx.x + 256] = weights[b * TDIM + 256 + threadIdx.x];
    __syncthreads();

    const float* fp = feats + (size_t)b * TDIM * FEAT + f4;
    float ax = 0.f, ay = 0.f, az = 0.f, aw = 0.f;
    for (int t = 0; t < TDIM; ++t) {
        float4 v = *(const float4*)(fp + (size_t)t * FEAT);
        float w = wsm[t];
        ax += v.x * w; ay += v.y * w; az += v.z * w; aw += v.w * w;
    }
    float4 o = {ax, ay, az, aw};
    *(float4*)(out + (size_t)b * FEAT + f4) = o;
}

// ---------------------------------------------------------------------------
// Launch. d_out: [0, B*FEAT) attn_feats, [B*FEAT, +B*T) weights.
// d_out staging: Whb in weights region (dead after k2n); energies in attn
// region (dead after k3n). d_ws: packed bf16 U tiles (2 MB) + pooling
// partials (8 MB). Branch on host-constant ws_size (graph-safe).
// ---------------------------------------------------------------------------
extern "C" void kernel_launch(void* const* d_in, const int* in_sizes, int n_in,
                              void* d_out, int out_size, void* d_ws, size_t ws_size,
                              hipStream_t stream) {
    const float* hidden = (const float*)d_in[0];
    const float* feats  = (const float*)d_in[1];
    const float* W      = (const float*)d_in[2];
    const float* U      = (const float*)d_in[3];
    const float* bias   = (const float*)d_in[4];
    const float* wvec   = (const float*)d_in[5];

    float* out         = (float*)d_out;
    float* attn_out    = out;
    float* weights_out = out + (size_t)BATCH * FEAT;
    float* whb         = weights_out;  // staged (dead after k2n)
    float* energies    = attn_out;     // staged (dead after k3n)

    const size_t uN        = (size_t)KDIM * FEAT;
    const size_t uBytes    = uN * sizeof(unsigned short);
    const size_t poolBytes = (size_t)TCH * BATCH * FEAT * sizeof(float);
    const bool fast = ws_size >= uBytes + poolBytes;

    if (fast) {
        unsigned short* uBt = (unsigned short*)d_ws;
        float* pool4 = (float*)((char*)d_ws + uBytes);
        k0n<<<dim3(256 + 8192), 256, 0, stream>>>(U, hidden, W, bias, uBt, whb);
        k2n<<<dim3(MROWS / 128), 512, 0, stream>>>(feats, uBt, whb, wvec, energies);
        k3n<<<dim3(BATCH), 512, 0, stream>>>(energies, weights_out);
        k4n<<<dim3(TCH, BATCH), 256, 0, stream>>>(feats, weights_out, pool4);
        k5_reduce<<<dim3(BATCH * FEAT / 4 / 256), 256, 0, stream>>>(pool4, attn_out);
    } else {
        k1_whb<<<dim3(KDIM / 4, BATCH), 256, 0, stream>>>(hidden, W, bias, whb);
        k2_energy<<<dim3(MROWS / 128, KDIM / 128), 256, 0, stream>>>(
            feats, U, whb, wvec, energies);
        k3_softmax<<<dim3(BATCH), 512, 0, stream>>>(energies, weights_out);
        k4_direct<<<dim3(FEAT / 1024, BATCH), 256, 0, stream>>>(
            feats, weights_out, attn_out);
    }
}